// Round 5
// baseline (1529.985 us; speedup 1.0000x reference)
//
#include <hip/hip_runtime.h>
#include <hip/hip_bf16.h>
#include <stdint.h>
#include <stddef.h>

typedef __bf16 bf16_t;
typedef __bf16 bf16x4 __attribute__((ext_vector_type(4)));
typedef __bf16 bf16x8 __attribute__((ext_vector_type(8)));
typedef float floatx4 __attribute__((ext_vector_type(4)));

#define NN 20000
#define EE 320000
#define DD 512
#define CAP 96
#define BETA1 0.6931471805599453f
#define BETA2 0.40546510810816444f

// async global->LDS, 16B per lane. LDS dest must be wave-uniform base + lane*16.
__device__ __forceinline__ void gload16(const bf16_t* g, bf16_t* l) {
  __builtin_amdgcn_global_load_lds((const __attribute__((address_space(1))) uint32_t*)g,
                                   (__attribute__((address_space(3))) uint32_t*)l, 16, 0, 0);
}

// ------- bucket fill with degree count: esrc[dst*CAP + cnt[dst]++] = src -----
__global__ void bucket_kernel(const int* __restrict__ src, const int* __restrict__ dst,
                              int* __restrict__ cnt, int* __restrict__ esrc, int E) {
  int e = blockIdx.x * 256 + threadIdx.x;
  if (e < E) {
    int d = dst[e];
    int pos = atomicAdd(&cnt[d], 1);
    if (pos < CAP) esrc[d * CAP + pos] = src[e];
  }
}

__global__ void norm_kernel(const int* __restrict__ cnt, float* __restrict__ nrm, int n) {
  int i = blockIdx.x * 256 + threadIdx.x;
  if (i < n) nrm[i] = 1.0f / sqrtf(fmaxf((float)cnt[i], 1.0f));
}

// ---------------- f32 -> bf16 convert (4 elems/thread) ----------------
__global__ void cvt_kernel(const float* __restrict__ in, bf16_t* __restrict__ out, int n4) {
  int i = blockIdx.x * 256 + threadIdx.x;
  if (i < n4) {
    float4 v = ((const float4*)in)[i];
    bf16x4 o = {(bf16_t)v.x, (bf16_t)v.y, (bf16_t)v.z, (bf16_t)v.w};
    ((bf16x4*)out)[i] = o;
  }
}

// -------- build BT = [W1; W2]^T (bf16), BT[n][k], n<512, k<K; W* are f32 -----
__global__ void transpose_cat(const float* __restrict__ W1, const float* __restrict__ W2,
                              bf16_t* __restrict__ BT, int K) {
  __shared__ bf16_t tile[32][33];
  int k0 = blockIdx.y * 32;
  int n0 = blockIdx.x * 32;
  int tx = threadIdx.x, ty = threadIdx.y;
  const float* W = (k0 < 512) ? W1 : W2;
  int kk = (k0 < 512) ? k0 : (k0 - 512);
#pragma unroll
  for (int i = 0; i < 32; i += 8)
    tile[ty + i][tx] = (bf16_t)W[(size_t)(kk + ty + i) * 512 + n0 + tx];
  __syncthreads();
#pragma unroll
  for (int i = 0; i < 32; i += 8)
    BT[(size_t)(n0 + ty + i) * K + k0 + tx] = tile[tx][ty + i];
}

// ------------- bucket aggregate: one wave per dst node, lane owns 8 dims -----
// f = 0.9 * nrm[node] * sum_e nrm[src_e] * hin[src_e]
// Acat[node][0:512] = bf16(f)      (second half holds 0.1*h, layer-invariant)
__global__ __launch_bounds__(256) void aggregate_kernel(
    const bf16_t* __restrict__ hin, const float* __restrict__ nrm,
    const int* __restrict__ cnt, const int* __restrict__ esrc,
    bf16_t* __restrict__ Acat) {
  int node = blockIdx.x * 4 + (threadIdx.x >> 6);
  if (node >= NN) return;
  int lane = threadIdx.x & 63;
  const int* eb = esrc + (size_t)node * CAP;
  int n_e = cnt[node];
  n_e = n_e < CAP ? n_e : CAP;

  float acc[8] = {};
  bf16x8 vbuf[2];
  float nsbuf[2];
#pragma unroll
  for (int p = 0; p < 2; ++p) {
    if (p < n_e) {
      int s = eb[p];
      nsbuf[p] = nrm[s];
      vbuf[p] = *(const bf16x8*)(hin + (size_t)s * DD + lane * 8);
    }
  }
  for (int i = 0; i < n_e; ++i) {
    bf16x8 v = vbuf[i & 1];
    float ns = nsbuf[i & 1];
    int ip = i + 2;                     // depth-2 prefetch
    if (ip < n_e) {
      int s = eb[ip];
      nsbuf[i & 1] = nrm[s];
      vbuf[i & 1] = *(const bf16x8*)(hin + (size_t)s * DD + lane * 8);
    }
#pragma unroll
    for (int k = 0; k < 8; ++k) acc[k] += ns * (float)v[k];
  }

  float nd = 0.9f * nrm[node];
  bf16x8 ob;
#pragma unroll
  for (int k = 0; k < 8; ++k) ob[k] = (bf16_t)(nd * acc[k]);
  *(bf16x8*)(Acat + (size_t)node * 1024 + lane * 8) = ob;
}

// -------- GEMM: C = A(MxK,bf16) @ B(Kx512), B given transposed BT[n][k] ------
// Tile 128x128, 4 waves (2x2 quadrants), dbuf LDS via global_load_lds.
// MODE 0: h = acc + bias -> outb bf16; acat2[row*1024+512+col] = bf16(0.1*h)
// MODE 1/2: fs = Acat[row][col] + Acat[row][512+col] (bf16 halves);
//           r = relu((1-beta)*fs + beta*acc + bias) -> MODE1 bf16 outb, MODE2 f32 outf
template <int MODE>
__global__ __launch_bounds__(256) void gemm_kernel(
    const bf16_t* __restrict__ A, const bf16_t* __restrict__ BT,
    int lda, int ldb, int K, int M,
    const float* __restrict__ bias,
    const bf16_t* __restrict__ acat_ro, float beta,
    float* __restrict__ outf, bf16_t* __restrict__ outb,
    bf16_t* __restrict__ acat2) {
  __shared__ bf16_t As[2][128 * 32];   // 8 KB per buf
  __shared__ bf16_t Bs[2][128 * 32];   // 8 KB per buf

  const int t = threadIdx.x;
  const int lane = t & 63;
  const int w = t >> 6;
  const int wm = w & 1, wn = w >> 1;
  const int quad = lane >> 4, m16 = lane & 15;
  const int m0 = blockIdx.y * 128;
  const int n0 = blockIdx.x * 128;

  // staging: 512 chunks of 16B per matrix; thread t does chunks t and t+256.
  // chunk c: row r=c>>2, 16B-chunk kc=(c&3)^((r>>1)&3)  (kc identical for c and c+256)
  const int r0 = t >> 2;
  const int kc = (t & 3) ^ ((r0 >> 1) & 3);
  int ar0 = m0 + r0;       ar0 = ar0 < M ? ar0 : M - 1;
  int ar1 = m0 + r0 + 64;  ar1 = ar1 < M ? ar1 : M - 1;
  const bf16_t* agp0 = A + (size_t)ar0 * lda + kc * 8;
  const bf16_t* agp1 = A + (size_t)ar1 * lda + kc * 8;
  const bf16_t* bgp0 = BT + (size_t)(n0 + r0) * ldb + kc * 8;
  const bf16_t* bgp1 = BT + (size_t)(n0 + 64 + r0) * ldb + kc * 8;

  floatx4 acc[4][4] = {};
  const int niter = K >> 5;

  // stage buffer 0
  gload16(agp0, &As[0][t * 8]);
  gload16(agp1, &As[0][(t + 256) * 8]);
  gload16(bgp0, &Bs[0][t * 8]);
  gload16(bgp1, &Bs[0][(t + 256) * 8]);

  for (int kt = 0; kt < niter; ++kt) {
    __syncthreads();               // drains buf kt's loads
    const int b = kt & 1;
    if (kt + 1 < niter) {          // prefetch next buffer during compute
      const int nb = b ^ 1;
      const int ko = (kt + 1) * 32;
      gload16(agp0 + ko, &As[nb][t * 8]);
      gload16(agp1 + ko, &As[nb][(t + 256) * 8]);
      gload16(bgp0 + ko, &Bs[nb][t * 8]);
      gload16(bgp1 + ko, &Bs[nb][(t + 256) * 8]);
    }

    bf16x8 af[4], bfr[4];
#pragma unroll
    for (int i = 0; i < 4; ++i) {
      int arow = wm * 64 + i * 16 + m16;
      int ac = quad ^ ((arow >> 1) & 3);
      af[i] = *(const bf16x8*)(&As[b][(arow * 4 + ac) * 8]);
      int brow = wn * 64 + i * 16 + m16;
      int bc = quad ^ ((brow >> 1) & 3);
      bfr[i] = *(const bf16x8*)(&Bs[b][(brow * 4 + bc) * 8]);
    }
#pragma unroll
    for (int i = 0; i < 4; ++i)
#pragma unroll
      for (int j = 0; j < 4; ++j)
        acc[i][j] = __builtin_amdgcn_mfma_f32_16x16x32_bf16(af[i], bfr[j], acc[i][j], 0, 0, 0);
  }

  // epilogue: C/D layout col = lane&15, row = quad*4 + reg
#pragma unroll
  for (int i = 0; i < 4; ++i) {
#pragma unroll
    for (int j = 0; j < 4; ++j) {
      int col = n0 + wn * 64 + j * 16 + m16;
      float bv = bias[col];
#pragma unroll
      for (int p = 0; p < 4; ++p) {
        int row = m0 + wm * 64 + i * 16 + quad * 4 + p;
        if (row < M) {
          size_t idx = (size_t)row * DD + col;
          float v = acc[i][j][p];
          if constexpr (MODE == 0) {
            float hv = v + bv;
            outb[idx] = (bf16_t)hv;
            acat2[(size_t)row * 1024 + 512 + col] = (bf16_t)(0.1f * hv);
          } else {
            float fsv = (float)acat_ro[(size_t)row * 1024 + col] +
                        (float)acat_ro[(size_t)row * 1024 + 512 + col];
            float r = (1.0f - beta) * fsv + beta * v + bv;
            r = fmaxf(r, 0.0f);
            if constexpr (MODE == 1) outb[idx] = (bf16_t)r;
            else outf[idx] = r;
          }
        }
      }
    }
  }
}

extern "C" void kernel_launch(void* const* d_in, const int* in_sizes, int n_in,
                              void* d_out, int out_size, void* d_ws, size_t ws_size,
                              hipStream_t stream) {
  const float* feat = (const float*)d_in[0];
  const int* src = (const int*)d_in[1];
  const int* dst = (const int*)d_in[2];
  const float* fc_w = (const float*)d_in[3];
  const float* fc_b = (const float*)d_in[4];
  const float* w1_1 = (const float*)d_in[5];
  const float* w2_1 = (const float*)d_in[6];
  const float* b_1  = (const float*)d_in[7];
  const float* w1_2 = (const float*)d_in[8];
  const float* w2_2 = (const float*)d_in[9];
  const float* b_2  = (const float*)d_in[10];
  float* out = (float*)d_out;

  char* ws = (char*)d_ws;
  size_t off = 0;
  auto alloc = [&](size_t bytes) {
    char* p = ws + off;
    off += (bytes + 255) & ~(size_t)255;
    return p;
  };
  const size_t NDf = (size_t)NN * DD;               // 10.24M elements
  bf16_t* h_bf   = (bf16_t*)alloc(NDf * sizeof(bf16_t));        // 20.48 MB
  bf16_t* res_bf = (bf16_t*)alloc(NDf * sizeof(bf16_t));        // 20.48 MB
  bf16_t* featb  = (bf16_t*)alloc(NDf * sizeof(bf16_t));        // 20.48 MB
  bf16_t* Acat   = (bf16_t*)alloc((size_t)NN * 1024 * sizeof(bf16_t));  // 40.96 MB
  bf16_t* BW0    = (bf16_t*)alloc((size_t)512 * 512 * sizeof(bf16_t));
  bf16_t* BT1    = (bf16_t*)alloc((size_t)512 * 1024 * sizeof(bf16_t));
  bf16_t* BT2    = (bf16_t*)alloc((size_t)512 * 1024 * sizeof(bf16_t));
  int*    cnt    = (int*)alloc((size_t)NN * sizeof(int));
  float*  nrm    = (float*)alloc((size_t)NN * sizeof(float));
  int*    esrc   = (int*)alloc((size_t)NN * CAP * sizeof(int)); // 7.68 MB

  // bucket build (counts + slots in one pass) + norm
  hipMemsetAsync(cnt, 0, (size_t)NN * sizeof(int), stream);
  bucket_kernel<<<(EE + 255) / 256, 256, 0, stream>>>(src, dst, cnt, esrc, EE);
  norm_kernel<<<(NN + 255) / 256, 256, 0, stream>>>(cnt, nrm, NN);

  // input conversions: feat -> bf16, fc_w -> bf16 (already B^T layout)
  cvt_kernel<<<(int)(NDf / 4 / 256), 256, 0, stream>>>(feat, featb, (int)(NDf / 4));
  cvt_kernel<<<(512 * 512 / 4) / 256, 256, 0, stream>>>(fc_w, BW0, 512 * 512 / 4);

  // weight transposes+convert for layer GEMMs
  transpose_cat<<<dim3(16, 32), dim3(32, 8), 0, stream>>>(w1_1, w2_1, BT1, 1024);
  transpose_cat<<<dim3(16, 32), dim3(32, 8), 0, stream>>>(w1_2, w2_2, BT2, 1024);

  dim3 ggrid(4, 157);  // 512/128 n-tiles, ceil(20000/128) m-tiles

  // h = feat @ fc_w^T + fc_b  (stores h_bf AND Acat second half = 0.1*h)
  gemm_kernel<0><<<ggrid, 256, 0, stream>>>(featb, BW0, 512, 512, 512, NN, fc_b,
                                            nullptr, 0.0f, nullptr, h_bf, Acat);

  // ---- layer 1 ----
  aggregate_kernel<<<(NN + 3) / 4, 256, 0, stream>>>(h_bf, nrm, cnt, esrc, Acat);
  gemm_kernel<1><<<ggrid, 256, 0, stream>>>(Acat, BT1, 1024, 1024, 1024, NN, b_1,
                                            Acat, BETA1, nullptr, res_bf, nullptr);

  // ---- layer 2 ----
  aggregate_kernel<<<(NN + 3) / 4, 256, 0, stream>>>(res_bf, nrm, cnt, esrc, Acat);
  gemm_kernel<2><<<ggrid, 256, 0, stream>>>(Acat, BT2, 1024, 1024, 1024, NN, b_2,
                                            Acat, BETA2, out, nullptr, nullptr);
}

// Round 6
// 412.199 us; speedup vs baseline: 3.7118x; 3.7118x over previous
//
#include <hip/hip_runtime.h>
#include <hip/hip_bf16.h>
#include <stdint.h>
#include <stddef.h>

typedef __bf16 bf16_t;
typedef __bf16 bf16x4 __attribute__((ext_vector_type(4)));
typedef __bf16 bf16x8 __attribute__((ext_vector_type(8)));
typedef float floatx4 __attribute__((ext_vector_type(4)));

#define NN 20000
#define EE 320000
#define DD 512
#define CAP 96
#define BETA1 0.6931471805599453f
#define BETA2 0.40546510810816444f

// async global->LDS, 16B per lane. LDS dest must be wave-uniform base + lane*16.
__device__ __forceinline__ void gload16(const bf16_t* g, bf16_t* l) {
  __builtin_amdgcn_global_load_lds((const __attribute__((address_space(1))) uint32_t*)g,
                                   (__attribute__((address_space(3))) uint32_t*)l, 16, 0, 0);
}

// ------- bucket fill with degree count: esrc[dst*CAP + cnt[dst]++] = src -----
__global__ void bucket_kernel(const int* __restrict__ src, const int* __restrict__ dst,
                              int* __restrict__ cnt, int* __restrict__ esrc, int E) {
  int e = blockIdx.x * 256 + threadIdx.x;
  if (e < E) {
    int d = dst[e];
    int pos = atomicAdd(&cnt[d], 1);
    if (pos < CAP) esrc[d * CAP + pos] = src[e];
  }
}

__global__ void norm_kernel(const int* __restrict__ cnt, float* __restrict__ nrm, int n) {
  int i = blockIdx.x * 256 + threadIdx.x;
  if (i < n) nrm[i] = 1.0f / sqrtf(fmaxf((float)cnt[i], 1.0f));
}

// ---------------- f32 -> bf16 convert (4 elems/thread) ----------------
__global__ void cvt_kernel(const float* __restrict__ in, bf16_t* __restrict__ out, int n4) {
  int i = blockIdx.x * 256 + threadIdx.x;
  if (i < n4) {
    float4 v = ((const float4*)in)[i];
    bf16x4 o = {(bf16_t)v.x, (bf16_t)v.y, (bf16_t)v.z, (bf16_t)v.w};
    ((bf16x4*)out)[i] = o;
  }
}

// -------- build BT = [W1; W2]^T (bf16), BT[n][k], n<512, k<K; W* are f32 -----
__global__ void transpose_cat(const float* __restrict__ W1, const float* __restrict__ W2,
                              bf16_t* __restrict__ BT, int K) {
  __shared__ bf16_t tile[32][33];
  int k0 = blockIdx.y * 32;
  int n0 = blockIdx.x * 32;
  int tx = threadIdx.x, ty = threadIdx.y;
  const float* W = (k0 < 512) ? W1 : W2;
  int kk = (k0 < 512) ? k0 : (k0 - 512);
#pragma unroll
  for (int i = 0; i < 32; i += 8)
    tile[ty + i][tx] = (bf16_t)W[(size_t)(kk + ty + i) * 512 + n0 + tx];
  __syncthreads();
#pragma unroll
  for (int i = 0; i < 32; i += 8)
    BT[(size_t)(n0 + ty + i) * K + k0 + tx] = tile[tx][ty + i];
}

// ------------- bucket aggregate: one wave per dst node, lane owns 8 dims -----
// f = 0.9 * nrm[node] * sum_e nrm[src_e] * hin[src_e]
// Acat[node][0:512] = bf16(f)      (second half holds 0.1*h, layer-invariant)
// Depth-4 software pipeline with NAMED registers (no dynamic-index arrays —
// dynamic indexing forced a scratch spill in a previous revision: VGPR=32,
// 8.6x slowdown).
__global__ __launch_bounds__(256) void aggregate_kernel(
    const bf16_t* __restrict__ hin, const float* __restrict__ nrm,
    const int* __restrict__ cnt, const int* __restrict__ esrc,
    bf16_t* __restrict__ Acat) {
  int node = blockIdx.x * 4 + (threadIdx.x >> 6);
  if (node >= NN) return;
  int lane = threadIdx.x & 63;
  const int* eb = esrc + (size_t)node * CAP;
  int n_e = cnt[node];
  n_e = n_e < CAP ? n_e : CAP;

  float acc[8] = {};
  bf16x8 v0 = {}, v1 = {}, v2 = {}, v3 = {};
  float ns0 = 0, ns1 = 0, ns2 = 0, ns3 = 0;

#define LOADJ(j, idx)                                                  \
  {                                                                    \
    int s = eb[idx];                                                   \
    ns##j = nrm[s];                                                    \
    v##j = *(const bf16x8*)(hin + (size_t)s * DD + lane * 8);          \
  }

  if (0 < n_e) LOADJ(0, 0)
  if (1 < n_e) LOADJ(1, 1)
  if (2 < n_e) LOADJ(2, 2)
  if (3 < n_e) LOADJ(3, 3)

  for (int i = 0; i < n_e; i += 4) {
    {
      bf16x8 a = v0; float na = ns0;
      if (i + 4 < n_e) LOADJ(0, i + 4)
#pragma unroll
      for (int k = 0; k < 8; ++k) acc[k] += na * (float)a[k];
    }
    if (i + 1 < n_e) {
      bf16x8 a = v1; float na = ns1;
      if (i + 5 < n_e) LOADJ(1, i + 5)
#pragma unroll
      for (int k = 0; k < 8; ++k) acc[k] += na * (float)a[k];
    }
    if (i + 2 < n_e) {
      bf16x8 a = v2; float na = ns2;
      if (i + 6 < n_e) LOADJ(2, i + 6)
#pragma unroll
      for (int k = 0; k < 8; ++k) acc[k] += na * (float)a[k];
    }
    if (i + 3 < n_e) {
      bf16x8 a = v3; float na = ns3;
      if (i + 7 < n_e) LOADJ(3, i + 7)
#pragma unroll
      for (int k = 0; k < 8; ++k) acc[k] += na * (float)a[k];
    }
  }
#undef LOADJ

  float nd = 0.9f * nrm[node];
  bf16x8 ob;
#pragma unroll
  for (int k = 0; k < 8; ++k) ob[k] = (bf16_t)(nd * acc[k]);
  *(bf16x8*)(Acat + (size_t)node * 1024 + lane * 8) = ob;
}

// -------- GEMM: C = A(MxK,bf16) @ B(Kx512), B given transposed BT[n][k] ------
// Tile 128x128, 4 waves (2x2 quadrants), dbuf LDS via global_load_lds.
// MODE 0: h = acc + bias -> outb bf16; acat2[row*1024+512+col] = bf16(0.1*h)
// MODE 1/2: fs = Acat[row][col] + Acat[row][512+col] (bf16 halves);
//           r = relu((1-beta)*fs + beta*acc + bias) -> MODE1 bf16 outb, MODE2 f32 outf
template <int MODE>
__global__ __launch_bounds__(256) void gemm_kernel(
    const bf16_t* __restrict__ A, const bf16_t* __restrict__ BT,
    int lda, int ldb, int K, int M,
    const float* __restrict__ bias,
    const bf16_t* __restrict__ acat_ro, float beta,
    float* __restrict__ outf, bf16_t* __restrict__ outb,
    bf16_t* __restrict__ acat2) {
  __shared__ bf16_t As[2][128 * 32];   // 8 KB per buf
  __shared__ bf16_t Bs[2][128 * 32];   // 8 KB per buf

  const int t = threadIdx.x;
  const int lane = t & 63;
  const int w = t >> 6;
  const int wm = w & 1, wn = w >> 1;
  const int quad = lane >> 4, m16 = lane & 15;
  const int m0 = blockIdx.y * 128;
  const int n0 = blockIdx.x * 128;

  // staging: 512 chunks of 16B per matrix; thread t does chunks t and t+256.
  // chunk c: row r=c>>2, 16B-chunk kc=(c&3)^((r>>1)&3)  (kc identical for c and c+256)
  const int r0 = t >> 2;
  const int kc = (t & 3) ^ ((r0 >> 1) & 3);
  int ar0 = m0 + r0;       ar0 = ar0 < M ? ar0 : M - 1;
  int ar1 = m0 + r0 + 64;  ar1 = ar1 < M ? ar1 : M - 1;
  const bf16_t* agp0 = A + (size_t)ar0 * lda + kc * 8;
  const bf16_t* agp1 = A + (size_t)ar1 * lda + kc * 8;
  const bf16_t* bgp0 = BT + (size_t)(n0 + r0) * ldb + kc * 8;
  const bf16_t* bgp1 = BT + (size_t)(n0 + 64 + r0) * ldb + kc * 8;

  floatx4 acc[4][4] = {};
  const int niter = K >> 5;

  // stage buffer 0
  gload16(agp0, &As[0][t * 8]);
  gload16(agp1, &As[0][(t + 256) * 8]);
  gload16(bgp0, &Bs[0][t * 8]);
  gload16(bgp1, &Bs[0][(t + 256) * 8]);

  for (int kt = 0; kt < niter; ++kt) {
    __syncthreads();               // drains buf kt's loads
    const int b = kt & 1;
    if (kt + 1 < niter) {          // prefetch next buffer during compute
      const int nb = b ^ 1;
      const int ko = (kt + 1) * 32;
      gload16(agp0 + ko, &As[nb][t * 8]);
      gload16(agp1 + ko, &As[nb][(t + 256) * 8]);
      gload16(bgp0 + ko, &Bs[nb][t * 8]);
      gload16(bgp1 + ko, &Bs[nb][(t + 256) * 8]);
    }

    bf16x8 af[4], bfr[4];
#pragma unroll
    for (int i = 0; i < 4; ++i) {
      int arow = wm * 64 + i * 16 + m16;
      int ac = quad ^ ((arow >> 1) & 3);
      af[i] = *(const bf16x8*)(&As[b][(arow * 4 + ac) * 8]);
      int brow = wn * 64 + i * 16 + m16;
      int bc = quad ^ ((brow >> 1) & 3);
      bfr[i] = *(const bf16x8*)(&Bs[b][(brow * 4 + bc) * 8]);
    }
#pragma unroll
    for (int i = 0; i < 4; ++i)
#pragma unroll
      for (int j = 0; j < 4; ++j)
        acc[i][j] = __builtin_amdgcn_mfma_f32_16x16x32_bf16(af[i], bfr[j], acc[i][j], 0, 0, 0);
  }

  // epilogue: C/D layout col = lane&15, row = quad*4 + reg
#pragma unroll
  for (int i = 0; i < 4; ++i) {
#pragma unroll
    for (int j = 0; j < 4; ++j) {
      int col = n0 + wn * 64 + j * 16 + m16;
      float bv = bias[col];
#pragma unroll
      for (int p = 0; p < 4; ++p) {
        int row = m0 + wm * 64 + i * 16 + quad * 4 + p;
        if (row < M) {
          size_t idx = (size_t)row * DD + col;
          float v = acc[i][j][p];
          if constexpr (MODE == 0) {
            float hv = v + bv;
            outb[idx] = (bf16_t)hv;
            acat2[(size_t)row * 1024 + 512 + col] = (bf16_t)(0.1f * hv);
          } else {
            float fsv = (float)acat_ro[(size_t)row * 1024 + col] +
                        (float)acat_ro[(size_t)row * 1024 + 512 + col];
            float r = (1.0f - beta) * fsv + beta * v + bv;
            r = fmaxf(r, 0.0f);
            if constexpr (MODE == 1) outb[idx] = (bf16_t)r;
            else outf[idx] = r;
          }
        }
      }
    }
  }
}

extern "C" void kernel_launch(void* const* d_in, const int* in_sizes, int n_in,
                              void* d_out, int out_size, void* d_ws, size_t ws_size,
                              hipStream_t stream) {
  const float* feat = (const float*)d_in[0];
  const int* src = (const int*)d_in[1];
  const int* dst = (const int*)d_in[2];
  const float* fc_w = (const float*)d_in[3];
  const float* fc_b = (const float*)d_in[4];
  const float* w1_1 = (const float*)d_in[5];
  const float* w2_1 = (const float*)d_in[6];
  const float* b_1  = (const float*)d_in[7];
  const float* w1_2 = (const float*)d_in[8];
  const float* w2_2 = (const float*)d_in[9];
  const float* b_2  = (const float*)d_in[10];
  float* out = (float*)d_out;

  char* ws = (char*)d_ws;
  size_t off = 0;
  auto alloc = [&](size_t bytes) {
    char* p = ws + off;
    off += (bytes + 255) & ~(size_t)255;
    return p;
  };
  const size_t NDf = (size_t)NN * DD;               // 10.24M elements
  bf16_t* h_bf   = (bf16_t*)alloc(NDf * sizeof(bf16_t));        // 20.48 MB
  bf16_t* res_bf = (bf16_t*)alloc(NDf * sizeof(bf16_t));        // 20.48 MB
  bf16_t* featb  = (bf16_t*)alloc(NDf * sizeof(bf16_t));        // 20.48 MB
  bf16_t* Acat   = (bf16_t*)alloc((size_t)NN * 1024 * sizeof(bf16_t));  // 40.96 MB
  bf16_t* BW0    = (bf16_t*)alloc((size_t)512 * 512 * sizeof(bf16_t));
  bf16_t* BT1    = (bf16_t*)alloc((size_t)512 * 1024 * sizeof(bf16_t));
  bf16_t* BT2    = (bf16_t*)alloc((size_t)512 * 1024 * sizeof(bf16_t));
  int*    cnt    = (int*)alloc((size_t)NN * sizeof(int));
  float*  nrm    = (float*)alloc((size_t)NN * sizeof(float));
  int*    esrc   = (int*)alloc((size_t)NN * CAP * sizeof(int)); // 7.68 MB

  // bucket build (counts + slots in one pass) + norm
  hipMemsetAsync(cnt, 0, (size_t)NN * sizeof(int), stream);
  bucket_kernel<<<(EE + 255) / 256, 256, 0, stream>>>(src, dst, cnt, esrc, EE);
  norm_kernel<<<(NN + 255) / 256, 256, 0, stream>>>(cnt, nrm, NN);

  // input conversions: feat -> bf16, fc_w -> bf16 (already B^T layout)
  cvt_kernel<<<(int)(NDf / 4 / 256), 256, 0, stream>>>(feat, featb, (int)(NDf / 4));
  cvt_kernel<<<(512 * 512 / 4) / 256, 256, 0, stream>>>(fc_w, BW0, 512 * 512 / 4);

  // weight transposes+convert for layer GEMMs
  transpose_cat<<<dim3(16, 32), dim3(32, 8), 0, stream>>>(w1_1, w2_1, BT1, 1024);
  transpose_cat<<<dim3(16, 32), dim3(32, 8), 0, stream>>>(w1_2, w2_2, BT2, 1024);

  dim3 ggrid(4, 157);  // 512/128 n-tiles, ceil(20000/128) m-tiles

  // h = feat @ fc_w^T + fc_b  (stores h_bf AND Acat second half = 0.1*h)
  gemm_kernel<0><<<ggrid, 256, 0, stream>>>(featb, BW0, 512, 512, 512, NN, fc_b,
                                            nullptr, 0.0f, nullptr, h_bf, Acat);

  // ---- layer 1 ----
  aggregate_kernel<<<(NN + 3) / 4, 256, 0, stream>>>(h_bf, nrm, cnt, esrc, Acat);
  gemm_kernel<1><<<ggrid, 256, 0, stream>>>(Acat, BT1, 1024, 1024, 1024, NN, b_1,
                                            Acat, BETA1, nullptr, res_bf, nullptr);

  // ---- layer 2 ----
  aggregate_kernel<<<(NN + 3) / 4, 256, 0, stream>>>(res_bf, nrm, cnt, esrc, Acat);
  gemm_kernel<2><<<ggrid, 256, 0, stream>>>(Acat, BT2, 1024, 1024, 1024, NN, b_2,
                                            Acat, BETA2, out, nullptr, nullptr);
}

// Round 7
// 379.859 us; speedup vs baseline: 4.0278x; 1.0851x over previous
//
#include <hip/hip_runtime.h>
#include <hip/hip_bf16.h>
#include <stdint.h>
#include <stddef.h>

typedef __bf16 bf16_t;
typedef __bf16 bf16x4 __attribute__((ext_vector_type(4)));
typedef __bf16 bf16x8 __attribute__((ext_vector_type(8)));
typedef float floatx4 __attribute__((ext_vector_type(4)));

#define NN 20000
#define EE 320000
#define DD 512
#define CAP 96
#define BETA1 0.6931471805599453f
#define BETA2 0.40546510810816444f

// async global->LDS, 16B per lane. LDS dest must be wave-uniform base + lane*16.
__device__ __forceinline__ void gload16(const bf16_t* g, bf16_t* l) {
  __builtin_amdgcn_global_load_lds((const __attribute__((address_space(1))) uint32_t*)g,
                                   (__attribute__((address_space(3))) uint32_t*)l, 16, 0, 0);
}

// ------- bucket fill with degree count: esrc[dst*CAP + cnt[dst]++] = src -----
__global__ void bucket_kernel(const int* __restrict__ src, const int* __restrict__ dst,
                              int* __restrict__ cnt, int* __restrict__ esrc, int E) {
  int e = blockIdx.x * 256 + threadIdx.x;
  if (e < E) {
    int d = dst[e];
    int pos = atomicAdd(&cnt[d], 1);
    if (pos < CAP) esrc[d * CAP + pos] = src[e];
  }
}

__global__ void norm_kernel(const int* __restrict__ cnt, float* __restrict__ nrm, int n) {
  int i = blockIdx.x * 256 + threadIdx.x;
  if (i < n) nrm[i] = 1.0f / sqrtf(fmaxf((float)cnt[i], 1.0f));
}

// ---------------- f32 -> bf16 convert (4 elems/thread) ----------------
__global__ void cvt_kernel(const float* __restrict__ in, bf16_t* __restrict__ out, int n4) {
  int i = blockIdx.x * 256 + threadIdx.x;
  if (i < n4) {
    float4 v = ((const float4*)in)[i];
    bf16x4 o = {(bf16_t)v.x, (bf16_t)v.y, (bf16_t)v.z, (bf16_t)v.w};
    ((bf16x4*)out)[i] = o;
  }
}

// -------- build BT = [W1; W2]^T (bf16), BT[n][k], n<512, k<K; W* are f32 -----
__global__ void transpose_cat(const float* __restrict__ W1, const float* __restrict__ W2,
                              bf16_t* __restrict__ BT, int K) {
  __shared__ bf16_t tile[32][33];
  int k0 = blockIdx.y * 32;
  int n0 = blockIdx.x * 32;
  int tx = threadIdx.x, ty = threadIdx.y;
  const float* W = (k0 < 512) ? W1 : W2;
  int kk = (k0 < 512) ? k0 : (k0 - 512);
#pragma unroll
  for (int i = 0; i < 32; i += 8)
    tile[ty + i][tx] = (bf16_t)W[(size_t)(kk + ty + i) * 512 + n0 + tx];
  __syncthreads();
#pragma unroll
  for (int i = 0; i < 32; i += 8)
    BT[(size_t)(n0 + ty + i) * K + k0 + tx] = tile[tx][ty + i];
}

// ------------- bucket aggregate: one wave per dst node, lane owns 8 dims -----
// f = 0.9 * nrm[node] * sum_e nrm[src_e] * hin[src_e]
// Acat[node][0:512] = bf16(f)      (second half holds 0.1*h, layer-invariant)
// Depth-4 software pipeline with NAMED registers (dynamic-index arrays spill
// to scratch: VGPR=32, 8.6x slowdown — round 5).
__global__ __launch_bounds__(256) void aggregate_kernel(
    const bf16_t* __restrict__ hin, const float* __restrict__ nrm,
    const int* __restrict__ cnt, const int* __restrict__ esrc,
    bf16_t* __restrict__ Acat) {
  int node = blockIdx.x * 4 + (threadIdx.x >> 6);
  if (node >= NN) return;
  int lane = threadIdx.x & 63;
  const int* eb = esrc + (size_t)node * CAP;
  int n_e = cnt[node];
  n_e = n_e < CAP ? n_e : CAP;

  float acc[8] = {};
  bf16x8 v0 = {}, v1 = {}, v2 = {}, v3 = {};
  float ns0 = 0, ns1 = 0, ns2 = 0, ns3 = 0;

#define LOADJ(j, idx)                                                  \
  {                                                                    \
    int s = eb[idx];                                                   \
    ns##j = nrm[s];                                                    \
    v##j = *(const bf16x8*)(hin + (size_t)s * DD + lane * 8);          \
  }

  if (0 < n_e) LOADJ(0, 0)
  if (1 < n_e) LOADJ(1, 1)
  if (2 < n_e) LOADJ(2, 2)
  if (3 < n_e) LOADJ(3, 3)

  for (int i = 0; i < n_e; i += 4) {
    {
      bf16x8 a = v0; float na = ns0;
      if (i + 4 < n_e) LOADJ(0, i + 4)
#pragma unroll
      for (int k = 0; k < 8; ++k) acc[k] += na * (float)a[k];
    }
    if (i + 1 < n_e) {
      bf16x8 a = v1; float na = ns1;
      if (i + 5 < n_e) LOADJ(1, i + 5)
#pragma unroll
      for (int k = 0; k < 8; ++k) acc[k] += na * (float)a[k];
    }
    if (i + 2 < n_e) {
      bf16x8 a = v2; float na = ns2;
      if (i + 6 < n_e) LOADJ(2, i + 6)
#pragma unroll
      for (int k = 0; k < 8; ++k) acc[k] += na * (float)a[k];
    }
    if (i + 3 < n_e) {
      bf16x8 a = v3; float na = ns3;
      if (i + 7 < n_e) LOADJ(3, i + 7)
#pragma unroll
      for (int k = 0; k < 8; ++k) acc[k] += na * (float)a[k];
    }
  }
#undef LOADJ

  float nd = 0.9f * nrm[node];
  bf16x8 ob;
#pragma unroll
  for (int k = 0; k < 8; ++k) ob[k] = (bf16_t)(nd * acc[k]);
  *(bf16x8*)(Acat + (size_t)node * 1024 + lane * 8) = ob;
}

// -------- GEMM: C = A(MxK,bf16) @ B(Kx512), B given transposed BT[n][k] ------
// Tile 64x128, 4 waves (2x2), dbuf LDS via global_load_lds, 1 barrier/iter.
// XCD swizzle: blocks sharing an m-tile get block IDs congruent mod 8 so
// round-robin XCD dispatch co-locates them on one XCD's L2 (A fetched once).
//   bIdx = (m%8) + 8*(n + 4*(m/8));  decode: m = (bIdx/32)*8 + bIdx%8, n = (bIdx/8)%4
// MODE 0: h = acc + bias -> outb bf16; acat2[row*1024+512+col] = bf16(0.1*h)
// MODE 1/2: fs = Acat[row][col] + Acat[row][512+col] (bf16 halves);
//           r = relu((1-beta)*fs + beta*acc + bias) -> MODE1 bf16 outb, MODE2 f32 outf
template <int MODE>
__global__ __launch_bounds__(256) void gemm_kernel(
    const bf16_t* __restrict__ A, const bf16_t* __restrict__ BT,
    int lda, int ldb, int K, int M,
    const float* __restrict__ bias,
    const bf16_t* __restrict__ acat_ro, float beta,
    float* __restrict__ outf, bf16_t* __restrict__ outb,
    bf16_t* __restrict__ acat2) {
  __shared__ bf16_t As[2][64 * 32];    // 4 KB per buf
  __shared__ bf16_t Bs[2][128 * 32];   // 8 KB per buf

  const int bid = blockIdx.x;
  const int mt = (bid >> 5) * 8 + (bid & 7);   // m-tile
  const int nt = (bid >> 3) & 3;               // n-tile
  const int m0 = mt * 64;
  if (m0 >= M) return;
  const int n0 = nt * 128;

  const int t = threadIdx.x;
  const int lane = t & 63;
  const int w = t >> 6;
  const int wm = w & 1, wn = w >> 1;
  const int quad = lane >> 4, m16 = lane & 15;

  // staging: chunk c -> row r=c>>2, 16B-chunk kc=(c&3)^((r>>1)&3)
  const int r0 = t >> 2;
  const int kc = (t & 3) ^ ((r0 >> 1) & 3);
  int arow_g = m0 + r0; arow_g = arow_g < M ? arow_g : M - 1;  // clamp OOB
  const bf16_t* agp  = A  + (size_t)arow_g * lda + kc * 8;
  const bf16_t* bgp0 = BT + (size_t)(n0 + r0) * ldb + kc * 8;
  const bf16_t* bgp1 = BT + (size_t)(n0 + 64 + r0) * ldb + kc * 8;

  floatx4 acc[2][4] = {};
  const int niter = K >> 5;

  // stage buffer 0
  gload16(agp,  &As[0][t * 8]);
  gload16(bgp0, &Bs[0][t * 8]);
  gload16(bgp1, &Bs[0][(t + 256) * 8]);

  for (int kt = 0; kt < niter; ++kt) {
    __syncthreads();   // drains buf kt's loads (issued one iter ago)
    const int b = kt & 1;
    if (kt + 1 < niter) {        // prefetch next buffer during compute
      const int nb = b ^ 1;
      const int ko = (kt + 1) * 32;
      gload16(agp + ko,  &As[nb][t * 8]);
      gload16(bgp0 + ko, &Bs[nb][t * 8]);
      gload16(bgp1 + ko, &Bs[nb][(t + 256) * 8]);
    }

    bf16x8 af[2], bfr[4];
#pragma unroll
    for (int i = 0; i < 2; ++i) {
      int arow = wm * 32 + i * 16 + m16;
      int ac = quad ^ ((arow >> 1) & 3);
      af[i] = *(const bf16x8*)(&As[b][(arow * 4 + ac) * 8]);
    }
#pragma unroll
    for (int j = 0; j < 4; ++j) {
      int brow = wn * 64 + j * 16 + m16;
      int bc = quad ^ ((brow >> 1) & 3);
      bfr[j] = *(const bf16x8*)(&Bs[b][(brow * 4 + bc) * 8]);
    }
#pragma unroll
    for (int i = 0; i < 2; ++i)
#pragma unroll
      for (int j = 0; j < 4; ++j)
        acc[i][j] = __builtin_amdgcn_mfma_f32_16x16x32_bf16(af[i], bfr[j], acc[i][j], 0, 0, 0);
  }

  // epilogue: C/D layout col = lane&15, row = quad*4 + reg
#pragma unroll
  for (int i = 0; i < 2; ++i) {
#pragma unroll
    for (int j = 0; j < 4; ++j) {
      int col = n0 + wn * 64 + j * 16 + m16;
      float bv = bias[col];
#pragma unroll
      for (int p = 0; p < 4; ++p) {
        int row = m0 + wm * 32 + i * 16 + quad * 4 + p;
        if (row < M) {
          size_t idx = (size_t)row * DD + col;
          float v = acc[i][j][p];
          if constexpr (MODE == 0) {
            float hv = v + bv;
            outb[idx] = (bf16_t)hv;
            acat2[(size_t)row * 1024 + 512 + col] = (bf16_t)(0.1f * hv);
          } else {
            float fsv = (float)acat_ro[(size_t)row * 1024 + col] +
                        (float)acat_ro[(size_t)row * 1024 + 512 + col];
            float r = (1.0f - beta) * fsv + beta * v + bv;
            r = fmaxf(r, 0.0f);
            if constexpr (MODE == 1) outb[idx] = (bf16_t)r;
            else outf[idx] = r;
          }
        }
      }
    }
  }
}

extern "C" void kernel_launch(void* const* d_in, const int* in_sizes, int n_in,
                              void* d_out, int out_size, void* d_ws, size_t ws_size,
                              hipStream_t stream) {
  const float* feat = (const float*)d_in[0];
  const int* src = (const int*)d_in[1];
  const int* dst = (const int*)d_in[2];
  const float* fc_w = (const float*)d_in[3];
  const float* fc_b = (const float*)d_in[4];
  const float* w1_1 = (const float*)d_in[5];
  const float* w2_1 = (const float*)d_in[6];
  const float* b_1  = (const float*)d_in[7];
  const float* w1_2 = (const float*)d_in[8];
  const float* w2_2 = (const float*)d_in[9];
  const float* b_2  = (const float*)d_in[10];
  float* out = (float*)d_out;

  char* ws = (char*)d_ws;
  size_t off = 0;
  auto alloc = [&](size_t bytes) {
    char* p = ws + off;
    off += (bytes + 255) & ~(size_t)255;
    return p;
  };
  const size_t NDf = (size_t)NN * DD;               // 10.24M elements
  bf16_t* h_bf   = (bf16_t*)alloc(NDf * sizeof(bf16_t));        // 20.48 MB
  bf16_t* res_bf = (bf16_t*)alloc(NDf * sizeof(bf16_t));        // 20.48 MB
  bf16_t* featb  = (bf16_t*)alloc(NDf * sizeof(bf16_t));        // 20.48 MB
  bf16_t* Acat   = (bf16_t*)alloc((size_t)NN * 1024 * sizeof(bf16_t));  // 40.96 MB
  bf16_t* BW0    = (bf16_t*)alloc((size_t)512 * 512 * sizeof(bf16_t));
  bf16_t* BT1    = (bf16_t*)alloc((size_t)512 * 1024 * sizeof(bf16_t));
  bf16_t* BT2    = (bf16_t*)alloc((size_t)512 * 1024 * sizeof(bf16_t));
  int*    cnt    = (int*)alloc((size_t)NN * sizeof(int));
  float*  nrm    = (float*)alloc((size_t)NN * sizeof(float));
  int*    esrc   = (int*)alloc((size_t)NN * CAP * sizeof(int)); // 7.68 MB

  // bucket build (counts + slots in one pass) + norm
  hipMemsetAsync(cnt, 0, (size_t)NN * sizeof(int), stream);
  bucket_kernel<<<(EE + 255) / 256, 256, 0, stream>>>(src, dst, cnt, esrc, EE);
  norm_kernel<<<(NN + 255) / 256, 256, 0, stream>>>(cnt, nrm, NN);

  // input conversions: feat -> bf16, fc_w -> bf16 (already B^T layout)
  cvt_kernel<<<(int)(NDf / 4 / 256), 256, 0, stream>>>(feat, featb, (int)(NDf / 4));
  cvt_kernel<<<(512 * 512 / 4) / 256, 256, 0, stream>>>(fc_w, BW0, 512 * 512 / 4);

  // weight transposes+convert for layer GEMMs
  transpose_cat<<<dim3(16, 32), dim3(32, 8), 0, stream>>>(w1_1, w2_1, BT1, 1024);
  transpose_cat<<<dim3(16, 32), dim3(32, 8), 0, stream>>>(w1_2, w2_2, BT2, 1024);

  // 313 m-tiles of 64 rows, 4 n-tiles; swizzled grid covers m<320 -> 1280 blocks
  const int gblocks = 1280;

  // h = feat @ fc_w^T + fc_b  (stores h_bf AND Acat second half = 0.1*h)
  gemm_kernel<0><<<gblocks, 256, 0, stream>>>(featb, BW0, 512, 512, 512, NN, fc_b,
                                              nullptr, 0.0f, nullptr, h_bf, Acat);

  // ---- layer 1 ----
  aggregate_kernel<<<(NN + 3) / 4, 256, 0, stream>>>(h_bf, nrm, cnt, esrc, Acat);
  gemm_kernel<1><<<gblocks, 256, 0, stream>>>(Acat, BT1, 1024, 1024, 1024, NN, b_1,
                                              Acat, BETA1, nullptr, res_bf, nullptr);

  // ---- layer 2 ----
  aggregate_kernel<<<(NN + 3) / 4, 256, 0, stream>>>(res_bf, nrm, cnt, esrc, Acat);
  gemm_kernel<2><<<gblocks, 256, 0, stream>>>(Acat, BT2, 1024, 1024, 1024, NN, b_2,
                                              Acat, BETA2, out, nullptr, nullptr);
}